// Round 6
// baseline (408.703 us; speedup 1.0000x reference)
//
#include <hip/hip_runtime.h>
#include <hip/hip_bf16.h>
#include <stdint.h>

#define BATCH 16
#define CIN   256
#define HH    112
#define WW    112
#define GROUPS 2
#define CG    128   // cin per group
#define COG   128   // cout per group
#define CK    32    // cin chunk per K-step

typedef __bf16 bf16x8 __attribute__((ext_vector_type(8)));
typedef float  f32x4  __attribute__((ext_vector_type(4)));

// ---- workspace layout ----
#define WB_BYTES   (GROUPS*3*3*COG*CG*2)        // 589824
#define ZBUF_OFF   WB_BYTES
#define ZBUF_BYTES 8192
#define XB_OFF     (ZBUF_OFF + ZBUF_BYTES)      // 598016
#define XB_BYTES   ((size_t)BATCH*HH*WW*CIN*2)  // 102760448
#define WS_NEED    ((size_t)XB_OFF + XB_BYTES)  // 103358464

__device__ inline void load_lds16(const void* g, void* l) {
    __builtin_amdgcn_global_load_lds(
        (const __attribute__((address_space(1))) void*)g,
        (__attribute__((address_space(3))) void*)l, 16, 0, 0);
}

// ---- pre-pass 1: weights OIHW fp32 -> [g][kh][kw][cout][cin] bf16 ----
__global__ __launch_bounds__(256) void k_wcvt(const float* __restrict__ w,
                                              ushort* __restrict__ wb) {
    int i = blockIdx.x * 256 + threadIdx.x;   // 294912 total
    int ci = i & 127;
    int t  = i >> 7;
    int co = t & 127;
    t >>= 7;                                  // t = g*9 + kh*3 + kw
    int kw = t % 3; t /= 3;
    int kh = t % 3;
    int g  = t / 3;
    int src = (((g*COG + co)*CG + ci)*3 + kh)*3 + kw;
    __hip_bfloat16 v = __float2bfloat16(w[src]);
    wb[i] = *reinterpret_cast<ushort*>(&v);
}

// ---- pre-pass 2: x NCHW fp32 -> NHWC bf16 (LDS transpose) ----
#define XPAD 113
__global__ __launch_bounds__(256) void k_xcvt(const float* __restrict__ x,
                                              ushort* __restrict__ xb) {
    __shared__ float tile[64 * XPAD];
    int bid = blockIdx.x;            // 16*112*4 = 7168
    int cc  = bid & 3;               // chunk of 64 channels
    int h   = (bid >> 2) % HH;
    int b   = bid / (4 * HH);
    int tid = threadIdx.x;

    const float* src = x + ((size_t)(b*CIN + cc*64) * HH + h) * WW;
    for (int tt = tid; tt < 64*28; tt += 256) {
        int c = tt / 28, v = tt % 28;
        float4 f = *reinterpret_cast<const float4*>(src + (size_t)c*HH*WW + v*4);
        float* d = &tile[c*XPAD + v*4];
        d[0]=f.x; d[1]=f.y; d[2]=f.z; d[3]=f.w;
    }
    __syncthreads();

    if (tid < 224) {
        int w = tid >> 1, half = tid & 1;
        ushort o[32];
#pragma unroll
        for (int j = 0; j < 32; ++j) {
            __hip_bfloat16 v = __float2bfloat16(tile[(half*32 + j)*XPAD + w]);
            o[j] = *reinterpret_cast<ushort*>(&v);
        }
        ushort* dst = xb + (((size_t)(b*HH + h)*WW + w)*CIN + cc*64 + half*32);
        const uint4* o4 = reinterpret_cast<const uint4*>(o);
        uint4* d4 = reinterpret_cast<uint4*>(dst);
        d4[0]=o4[0]; d4[1]=o4[1]; d4[2]=o4[2]; d4[3]=o4[3];
    }
}

// ---- one x-prefetch task: 16-px strip of one halo row (swizzled source) ----
__device__ inline void xpre_task(const ushort* __restrict__ xb, ushort* dstbuf,
                                 const ushort* __restrict__ zbuf,
                                 int b, int g, int oh0n, int cin, int t, int lane) {
    int rr = t / 7, ii = t % 7;
    int h  = oh0n - 1 + rr;
    int qv = lane >> 2;
    int w_in = ii*16 + qv;
    int ts = (lane & 3) ^ (((2*rr + 1 + qv) >> 1) & 3);
    const ushort* src = (h >= 0 && h < HH)
        ? xb + (((size_t)(b*HH + h)*WW + w_in)*CIN + g*CG + cin + ts*8)
        : zbuf + lane*8;
    load_lds16(src, dstbuf + (rr*114 + 1 + ii*16)*CK);
}

// ---- main kernel: persistent implicit-GEMM grouped conv ----
// LDS-traffic-reduction round: weights bypass LDS entirely (global->reg from
// L2-hot 590KB wb; each A-frag consumed once so LDS staging bought zero
// reuse). Per-wave per-tap LDS reads: 11 -> 7 (B only). LDS = xs dbuf only
// (87.5 KB); ONE barrier per cin-chunk (16 total). A prefetched 1 tap deep
// via named Acur/Anext (static indices only). B-path/swizzle/epilogue are
// byte-identical to r3's verified code (conflicts==0, absmax 0.0156).
__global__ __launch_bounds__(512, 2) void k_conv(const ushort* __restrict__ xb,
                                                 const ushort* __restrict__ wb,
                                                 const float* __restrict__ bias,
                                                 float* __restrict__ out,
                                                 const ushort* __restrict__ zbuf) {
    __shared__ __align__(16) ushort xs[2][6*114*CK];     // 2 x 43776 B

    int g   = blockIdx.x / 112;          // 224 = 2g * 16b * 7qb
    int rem = blockIdx.x % 112;
    int b   = rem / 7;
    int qb  = rem % 7;

    int tid  = threadIdx.x;
    int wave = tid >> 6;
    int lane = tid & 63;
    int wm   = wave >> 2;          // cout half (0..1), 64 couts
    int wr   = wave & 3;           // output row within quad (0..3)
    int l15  = lane & 15;
    int lk   = lane >> 4;

    // zero pad columns (w=0,113) of both x buffers: 2*6*2*32 = 768 slots
    for (int t = tid; t < 768; t += 512) {
        int buf = t / 384, r2 = t % 384;
        int rr = r2 / 64, wc = (r2 >> 5) & 1, ch = r2 & 31;
        xs[buf][(rr*114 + wc*113)*CK + ch] = 0;
    }

    // per-lane weight base: lane (l15 -> cout row, lk -> k-slot of 8 ch)
    const ushort* wgbase = wb + (size_t)g*9*COG*CG + (wm*64 + l15)*CG + lk*8;

    f32x4 acc[4][7];
#pragma unroll
    for (int m = 0; m < 4; ++m)
#pragma unroll
        for (int n = 0; n < 7; ++n) acc[m][n] = f32x4{0.f,0.f,0.f,0.f};

    // prologue: stage x chunk 0; preload A-frags for tap 0
    for (int t = wave; t < 42; t += 8)
        xpre_task(xb, xs[0], zbuf, b, g, qb*16, 0, t, lane);
    bf16x8 Acur[4], Anext[4];
#pragma unroll
    for (int m = 0; m < 4; ++m)
        Acur[m] = *reinterpret_cast<const bf16x8*>(wgbase + m*16*CG);
    __syncthreads();

    // CC: item e = CC>>2 (oh0 = qb*16+e*4), cin-chunk = CC&3
#pragma unroll 1
    for (int CC = 0; CC < 16; ++CC) {
        int oh0  = qb*16 + (CC >> 2)*4;
        int p0   = CC & 1;
        const ushort* xcur = xs[p0];
        int cin  = (CC & 3) * CK;
        int cinN = ((CC + 1) & 3) * CK;
        int oh0n = qb*16 + ((CC + 1) >> 2)*4;
        bool last = (CC == 15);

#pragma unroll
        for (int tap = 0; tap < 9; ++tap) {
            const int kh = tap / 3, kw = tap % 3;

            // 1) prefetch A for tap+1 (or next chunk's tap 0)
            if (!(last && tap == 8)) {
                const int ntap = (tap + 1) % 9;
                int ncin = (tap == 8) ? cinN : cin;
#pragma unroll
                for (int m = 0; m < 4; ++m)
                    Anext[m] = *reinterpret_cast<const bf16x8*>(
                        wgbase + (size_t)ntap*COG*CG + m*16*CG + ncin);
            }

            // 2) x-prefetch for next chunk: 42 tasks spread over taps 0..5
            if (tap < 6 && !last) {
                int t = wave + tap*8;
                if (t < 42)
                    xpre_task(xb, xs[p0^1], zbuf, b, g, oh0n, cinN, t, lane);
            }

            // 3) B fragments from LDS (verified swizzled path)
            int sB = lk ^ (((2*(wr + kh) + l15 + kw) >> 1) & 3);
            const ushort* bbase = xcur + ((wr + kh)*114 + l15 + kw)*CK + sB*8;
            bf16x8 bfr[7];
#pragma unroll
            for (int n = 0; n < 7; ++n)
                bfr[n] = *reinterpret_cast<const bf16x8*>(bbase + n*16*CK);

            // 4) 28 MFMAs
            __builtin_amdgcn_s_setprio(1);
#pragma unroll
            for (int m = 0; m < 4; ++m)
#pragma unroll
                for (int n = 0; n < 7; ++n)
                    acc[m][n] = __builtin_amdgcn_mfma_f32_16x16x32_bf16(
                        Acur[m], bfr[n], acc[m][n], 0, 0, 0);
            __builtin_amdgcn_s_setprio(0);

            // 5) rotate A prefetch (static indices; renamed by regalloc)
#pragma unroll
            for (int m = 0; m < 4; ++m) Acur[m] = Anext[m];
        }

        // end of item: epilogue (D: row=(lane>>4)*4+j -> cout, col=l15 -> ow)
        if ((CC & 3) == 3) {
            int oh = oh0 + wr;
#pragma unroll
            for (int m = 0; m < 4; ++m) {
                int cob = g*COG + wm*64 + m*16 + lk*4;
#pragma unroll
                for (int j = 0; j < 4; ++j) {
                    int co = cob + j;
                    float bv = bias[co];
                    float* orow = out + (((size_t)(b*CIN + co)*HH + oh)*WW);
#pragma unroll
                    for (int n = 0; n < 7; ++n)
                        orow[n*16 + l15] = acc[m][n][j] + bv;
                }
            }
#pragma unroll
            for (int m = 0; m < 4; ++m)
#pragma unroll
                for (int n = 0; n < 7; ++n) acc[m][n] = f32x4{0.f,0.f,0.f,0.f};
        }

        // publish xs[(CC+1)&1] (x-prefetch loads are ~1 chunk old -> cheap)
        __syncthreads();
    }
}

// ---- fallback: direct fp32 conv (used only if ws is too small) ----
__global__ __launch_bounds__(128) void k_direct(const float* __restrict__ x,
                                                const float* __restrict__ w,
                                                const float* __restrict__ bias,
                                                float* __restrict__ out) {
    int bid = blockIdx.x;          // B*Cout*H
    int oh  = bid % HH;
    int t   = bid / HH;
    int co  = t % CIN;
    int b   = t / CIN;
    int ow  = threadIdx.x;
    if (ow >= WW) return;
    int g = co / COG;
    float s = bias[co];
    const float* wp = w + (size_t)co*CG*9;
    const float* xp = x + ((size_t)b*CIN + g*CG)*HH*WW;
    for (int ci = 0; ci < CG; ++ci) {
        const float* xr = xp + (size_t)ci*HH*WW;
        const float* wr_ = wp + ci*9;
#pragma unroll
        for (int kh = 0; kh < 3; ++kh) {
            int ih = oh + kh - 1;
            if (ih < 0 || ih >= HH) continue;
#pragma unroll
            for (int kw = 0; kw < 3; ++kw) {
                int iw = ow + kw - 1;
                if (iw < 0 || iw >= WW) continue;
                s += xr[ih*WW + iw] * wr_[kh*3 + kw];
            }
        }
    }
    out[(((size_t)b*CIN + co)*HH + oh)*WW + ow] = s;
}

extern "C" void kernel_launch(void* const* d_in, const int* in_sizes, int n_in,
                              void* d_out, int out_size, void* d_ws, size_t ws_size,
                              hipStream_t stream) {
    const float* x    = (const float*)d_in[0];
    const float* w    = (const float*)d_in[1];
    const float* bias = (const float*)d_in[2];
    float* out        = (float*)d_out;

    if (ws_size >= WS_NEED) {
        ushort* wb   = (ushort*)d_ws;
        ushort* zb   = (ushort*)((char*)d_ws + ZBUF_OFF);
        ushort* xbuf = (ushort*)((char*)d_ws + XB_OFF);
        hipMemsetAsync(zb, 0, ZBUF_BYTES, stream);
        k_wcvt<<<1152, 256, 0, stream>>>(w, wb);
        k_xcvt<<<BATCH*HH*4, 256, 0, stream>>>(x, xbuf);
        k_conv<<<224, 512, 0, stream>>>(xbuf, wb, bias, out, zb);
    } else {
        k_direct<<<BATCH*CIN*HH, 128, 0, stream>>>(x, w, bias, out);
    }
}

// Round 7
// 298.529 us; speedup vs baseline: 1.3691x; 1.3691x over previous
//
#include <hip/hip_runtime.h>
#include <hip/hip_bf16.h>
#include <stdint.h>

#define BATCH 16
#define CIN   256
#define HH    112
#define WW    112
#define GROUPS 2
#define CG    128   // cin per group
#define COG   128   // cout per group
#define CK    32    // cin chunk per K-step

typedef __bf16 bf16x8 __attribute__((ext_vector_type(8)));
typedef float  f32x4  __attribute__((ext_vector_type(4)));

// ---- workspace layout ----
#define WB_BYTES   (GROUPS*3*3*COG*CG*2)        // 589824
#define ZBUF_OFF   WB_BYTES
#define ZBUF_BYTES 8192
#define XB_OFF     (ZBUF_OFF + ZBUF_BYTES)      // 598016
#define XB_BYTES   ((size_t)BATCH*HH*WW*CIN*2)  // 102760448
#define WS_NEED    ((size_t)XB_OFF + XB_BYTES)  // 103358464

__device__ inline void load_lds16(const void* g, void* l) {
    __builtin_amdgcn_global_load_lds(
        (const __attribute__((address_space(1))) void*)g,
        (__attribute__((address_space(3))) void*)l, 16, 0, 0);
}

// ---- pre-pass 1: weights OIHW fp32 -> [g][kh][kw][cout][cin] bf16 ----
__global__ __launch_bounds__(256) void k_wcvt(const float* __restrict__ w,
                                              ushort* __restrict__ wb) {
    int i = blockIdx.x * 256 + threadIdx.x;   // 294912 total
    int ci = i & 127;
    int t  = i >> 7;
    int co = t & 127;
    t >>= 7;                                  // t = g*9 + kh*3 + kw
    int kw = t % 3; t /= 3;
    int kh = t % 3;
    int g  = t / 3;
    int src = (((g*COG + co)*CG + ci)*3 + kh)*3 + kw;
    __hip_bfloat16 v = __float2bfloat16(w[src]);
    wb[i] = *reinterpret_cast<ushort*>(&v);
}

// ---- pre-pass 2: x NCHW fp32 -> NHWC bf16 (LDS transpose) ----
#define XPAD 113
__global__ __launch_bounds__(256) void k_xcvt(const float* __restrict__ x,
                                              ushort* __restrict__ xb) {
    __shared__ float tile[64 * XPAD];
    int bid = blockIdx.x;            // 16*112*4 = 7168
    int cc  = bid & 3;               // chunk of 64 channels
    int h   = (bid >> 2) % HH;
    int b   = bid / (4 * HH);
    int tid = threadIdx.x;

    const float* src = x + ((size_t)(b*CIN + cc*64) * HH + h) * WW;
    for (int tt = tid; tt < 64*28; tt += 256) {
        int c = tt / 28, v = tt % 28;
        float4 f = *reinterpret_cast<const float4*>(src + (size_t)c*HH*WW + v*4);
        float* d = &tile[c*XPAD + v*4];
        d[0]=f.x; d[1]=f.y; d[2]=f.z; d[3]=f.w;
    }
    __syncthreads();

    if (tid < 224) {
        int w = tid >> 1, half = tid & 1;
        ushort o[32];
#pragma unroll
        for (int j = 0; j < 32; ++j) {
            __hip_bfloat16 v = __float2bfloat16(tile[(half*32 + j)*XPAD + w]);
            o[j] = *reinterpret_cast<ushort*>(&v);
        }
        ushort* dst = xb + (((size_t)(b*HH + h)*WW + w)*CIN + cc*64 + half*32);
        const uint4* o4 = reinterpret_cast<const uint4*>(o);
        uint4* d4 = reinterpret_cast<uint4*>(dst);
        d4[0]=o4[0]; d4[1]=o4[1]; d4[2]=o4[2]; d4[3]=o4[3];
    }
}

// ---- stage one 3-tap weight group (swizzled source); 3 loads/thread ----
__device__ inline void stage_w3(const ushort* __restrict__ wb, ushort* dstbuf,
                                int g, int tap_base, int cin, int wave, int lane) {
    int co = wave*16 + (lane >> 2);
    int ts = (lane & 3) ^ ((lane >> 3) & 3);
#pragma unroll
    for (int i = 0; i < 3; ++i) {
        const ushort* src = wb + (((size_t)(g*9 + tap_base + i)*COG + co)*CG + cin + ts*8);
        load_lds16(src, dstbuf + (i*COG + wave*16)*CK);
    }
}

// ---- x-prefetch task 0..47 (42 real + 6 dummy for uniform vmcnt) ----
__device__ inline void xpre48(const ushort* __restrict__ xb, ushort* dstbuf,
                              ushort* dump, const ushort* __restrict__ zbuf,
                              int b, int g, int oh0n, int cin, int t, int lane) {
    if (t < 42) {
        int rr = t / 7, ii = t % 7;
        int h  = oh0n - 1 + rr;
        int qv = lane >> 2;
        int w_in = ii*16 + qv;
        int ts = (lane & 3) ^ (((2*rr + 1 + qv) >> 1) & 3);
        const ushort* src = (h >= 0 && h < HH)
            ? xb + (((size_t)(b*HH + h)*WW + w_in)*CIN + g*CG + cin + ts*8)
            : zbuf + lane*8;
        load_lds16(src, dstbuf + (rr*114 + 1 + ii*16)*CK);
    } else {
        load_lds16(zbuf + lane*8, dump);   // dummy: keeps per-wave counts uniform
    }
}

// counted vmem wait (literal N) — fenced both sides
#define WAITV(N)                                                            \
    __builtin_amdgcn_sched_barrier(0);                                      \
    asm volatile("s_waitcnt vmcnt(" #N ")" ::: "memory");                   \
    __builtin_amdgcn_sched_barrier(0);

// raw barrier: lgkm drain only (prefetch/stores stay in flight)
#define LGKM_BAR()                                                          \
    __builtin_amdgcn_sched_barrier(0);                                      \
    asm volatile("s_waitcnt lgkmcnt(0)" ::: "memory");                      \
    __builtin_amdgcn_sched_barrier(0);                                      \
    __builtin_amdgcn_s_barrier();                                           \
    __builtin_amdgcn_sched_barrier(0);

// one tap: 7 x-frags + 4 w-frags (11 ds_read_b128), 28 MFMA.
// OPERAND SWAP vs r3: mfma(xf, wf) -> D row-dim = px, col-dim = cout, so each
// lane holds 4 CONTIGUOUS px (lk*4+j) per cout -> f32x4 epilogue stores.
#define TAP(KH, KW, XCUR, WBUF)                                             \
  {                                                                         \
    int sB = lk ^ (((2*(wr + (KH)) + l15 + (KW)) >> 1) & 3);                \
    const ushort* bbase = (XCUR) + ((wr + (KH))*114 + l15 + (KW))*CK + sB*8;\
    bf16x8 xf[7];                                                           \
    _Pragma("unroll")                                                       \
    for (int i = 0; i < 7; ++i)                                             \
      xf[i] = *reinterpret_cast<const bf16x8*>(bbase + i*16*CK);            \
    const ushort* abase = (WBUF) + ((KW)*COG + wm*64 + l15)*CK + sA*8;      \
    __builtin_amdgcn_s_setprio(1);                                          \
    _Pragma("unroll")                                                       \
    for (int u = 0; u < 4; ++u) {                                           \
      bf16x8 wf = *reinterpret_cast<const bf16x8*>(abase + u*16*CK);        \
      _Pragma("unroll")                                                     \
      for (int i = 0; i < 7; ++i)                                           \
        acc[i][u] = __builtin_amdgcn_mfma_f32_16x16x32_bf16(                \
            xf[i], wf, acc[i][u], 0, 0, 0);                                 \
    }                                                                       \
    __builtin_amdgcn_s_setprio(0);                                          \
  }

#define GROUP3(KH, XCUR, WBUF) TAP(KH,0,XCUR,WBUF) TAP(KH,1,XCUR,WBUF) TAP(KH,2,XCUR,WBUF)

// ---- main kernel: persistent implicit-GEMM grouped conv, counted-vmcnt ----
// r3's verified LDS/swizzle/fragment scheme + T4 barrier discipline: every
// barrier is raw s_barrier + lgkmcnt(0); vmem waits are COUNTED so prefetch
// and the 28 dwordx4 epilogue stores stay in flight across barriers.
// Per-thread issue counts/pass: ph1 {w3:3, x:3}, ph2 {w3:3, x:3}, ph3 {w3:3};
// waits: ph1 vmcnt(6) (34 after item stores), ph2 vmcnt(9), ph3 vmcnt(6).
__global__ __launch_bounds__(512, 2) void k_conv(const ushort* __restrict__ xb,
                                                 const ushort* __restrict__ wb,
                                                 const float* __restrict__ bias,
                                                 float* __restrict__ out,
                                                 const ushort* __restrict__ zbuf) {
    __shared__ __align__(16) ushort xs[2][6*114*CK];     // 2 x 43776 B
    __shared__ __align__(16) ushort wsb[2][3*COG*CK];    // 2 x 24576 B
    __shared__ __align__(16) ushort dump[512];           // dummy-task sink (1KB)

    int g   = blockIdx.x / 112;          // 224 = 2g * 16b * 7qb
    int rem = blockIdx.x % 112;
    int b   = rem / 7;
    int qb  = rem % 7;

    int tid  = threadIdx.x;
    int wave = tid >> 6;
    int lane = tid & 63;
    int wm   = wave >> 2;          // cout half (0..1), 64 couts
    int wr   = wave & 3;           // output row within quad (0..3)
    int l15  = lane & 15;
    int lk   = lane >> 4;
    int sA   = lk ^ ((l15 >> 1) & 3);    // weight-read slot

    // zero pad columns (w=0,113) of both x buffers
    for (int t = tid; t < 768; t += 512) {
        int buf = t / 384, r2 = t % 384;
        int rr = r2 / 64, wc = (r2 >> 5) & 1, ch = r2 & 31;
        xs[buf][(rr*114 + wc*113)*CK + ch] = 0;
    }

    // bias per lane: co = g*COG + wm*64 + u*16 + l15 (constant all kernel)
    float bvreg[4];
#pragma unroll
    for (int u = 0; u < 4; ++u)
        bvreg[u] = bias[g*COG + wm*64 + u*16 + l15];

    f32x4 acc[7][4];
#pragma unroll
    for (int i = 0; i < 7; ++i)
#pragma unroll
        for (int u = 0; u < 4; ++u) acc[i][u] = f32x4{0.f,0.f,0.f,0.f};

    // prologue: stage x chunk 0 (48 tasks) + w taps 0-2; full drain once
    for (int k2 = 0; k2 < 6; ++k2)
        xpre48(xb, xs[0], dump, zbuf, b, g, qb*16, 0, wave + 8*k2, lane);
    stage_w3(wb, wsb[0], g, 0, 0, wave, lane);
    WAITV(0)
    LGKM_BAR()

    // CC: item e = CC>>2 (oh0 = qb*16+e*4), cin-chunk = CC&3
#pragma unroll 1
    for (int CC = 0; CC < 16; ++CC) {
        int oh0  = qb*16 + (CC >> 2)*4;
        int p    = CC & 1;                  // xs parity (== wsb parity qs)
        const ushort* xcur = xs[p];
        ushort* xnxt = xs[p^1];
        int cin  = (CC & 3) * CK;
        int cinN = ((CC + 1) & 3) * CK;
        int oh0n = qb*16 + ((CC + 1) >> 2)*4;  // CC=15: h-guard makes it safe

        // ---- ph1: reads wsb[p]; stage taps3-5 -> wsb[p^1]; x tasks 0-23
        stage_w3(wb, wsb[p^1], g, 3, cin, wave, lane);
#pragma unroll
        for (int k2 = 0; k2 < 3; ++k2)
            xpre48(xb, xnxt, dump, zbuf, b, g, oh0n, cinN, wave*3 + k2, lane);
        if (CC != 0 && (CC & 3) == 0) { WAITV(34) } else { WAITV(6) }
        GROUP3(0, xcur, wsb[p])
        LGKM_BAR()

        // ---- ph2: reads wsb[p^1]; stage taps6-8 -> wsb[p]; x tasks 24-47
        stage_w3(wb, wsb[p], g, 6, cin, wave, lane);
#pragma unroll
        for (int k2 = 0; k2 < 3; ++k2)
            xpre48(xb, xnxt, dump, zbuf, b, g, oh0n, cinN, 24 + wave*3 + k2, lane);
        WAITV(9)
        GROUP3(1, xcur, wsb[p^1])
        LGKM_BAR()

        // ---- ph3: reads wsb[p]; stage next chunk taps0-2 -> wsb[p^1]
        stage_w3(wb, wsb[p^1], g, 0, cinN, wave, lane);
        WAITV(6)
        GROUP3(2, xcur, wsb[p])

        // end of item: 28 dwordx4 stores, left in flight across barriers
        if ((CC & 3) == 3) {
            int oh = oh0 + wr;
#pragma unroll
            for (int u = 0; u < 4; ++u) {
                int co = g*COG + wm*64 + u*16 + l15;
                float bv = bvreg[u];
                float* obase = out + (((size_t)(b*CIN + co)*HH + oh)*WW + lk*4);
#pragma unroll
                for (int i = 0; i < 7; ++i) {
                    f32x4 v;
                    v[0] = acc[i][u][0] + bv;
                    v[1] = acc[i][u][1] + bv;
                    v[2] = acc[i][u][2] + bv;
                    v[3] = acc[i][u][3] + bv;
                    *reinterpret_cast<f32x4*>(obase + i*16) = v;
                    acc[i][u] = f32x4{0.f,0.f,0.f,0.f};
                }
            }
        }
        LGKM_BAR()
    }
}

// ---- fallback: direct fp32 conv (used only if ws is too small) ----
__global__ __launch_bounds__(128) void k_direct(const float* __restrict__ x,
                                                const float* __restrict__ w,
                                                const float* __restrict__ bias,
                                                float* __restrict__ out) {
    int bid = blockIdx.x;          // B*Cout*H
    int oh  = bid % HH;
    int t   = bid / HH;
    int co  = t % CIN;
    int b   = t / CIN;
    int ow  = threadIdx.x;
    if (ow >= WW) return;
    int g = co / COG;
    float s = bias[co];
    const float* wp = w + (size_t)co*CG*9;
    const float* xp = x + ((size_t)b*CIN + g*CG)*HH*WW;
    for (int ci = 0; ci < CG; ++ci) {
        const float* xr = xp + (size_t)ci*HH*WW;
        const float* wr_ = wp + ci*9;
#pragma unroll
        for (int kh = 0; kh < 3; ++kh) {
            int ih = oh + kh - 1;
            if (ih < 0 || ih >= HH) continue;
#pragma unroll
            for (int kw = 0; kw < 3; ++kw) {
                int iw = ow + kw - 1;
                if (iw < 0 || iw >= WW) continue;
                s += xr[ih*WW + iw] * wr_[kh*3 + kw];
            }
        }
    }
    out[(((size_t)b*CIN + co)*HH + oh)*WW + ow] = s;
}

extern "C" void kernel_launch(void* const* d_in, const int* in_sizes, int n_in,
                              void* d_out, int out_size, void* d_ws, size_t ws_size,
                              hipStream_t stream) {
    const float* x    = (const float*)d_in[0];
    const float* w    = (const float*)d_in[1];
    const float* bias = (const float*)d_in[2];
    float* out        = (float*)d_out;

    if (ws_size >= WS_NEED) {
        ushort* wb   = (ushort*)d_ws;
        ushort* zb   = (ushort*)((char*)d_ws + ZBUF_OFF);
        ushort* xbuf = (ushort*)((char*)d_ws + XB_OFF);
        hipMemsetAsync(zb, 0, ZBUF_BYTES, stream);
        k_wcvt<<<1152, 256, 0, stream>>>(w, wb);
        k_xcvt<<<BATCH*HH*4, 256, 0, stream>>>(x, xbuf);
        k_conv<<<224, 512, 0, stream>>>(xbuf, wb, bias, out, zb);
    } else {
        k_direct<<<BATCH*CIN*HH, 128, 0, stream>>>(x, w, bias, out);
    }
}

// Round 8
// 235.168 us; speedup vs baseline: 1.7379x; 1.2694x over previous
//
#include <hip/hip_runtime.h>
#include <hip/hip_bf16.h>
#include <stdint.h>

#define BATCH 16
#define CIN   256
#define HH    112
#define WW    112
#define GROUPS 2
#define CG    128   // cin per group
#define COG   128   // cout per group
#define CK    32    // cin chunk per K-step

typedef __bf16 bf16x8 __attribute__((ext_vector_type(8)));
typedef float  f32x4  __attribute__((ext_vector_type(4)));

// ---- workspace layout ----
#define WB_BYTES   (GROUPS*3*3*COG*CG*2)        // 589824
#define ZBUF_OFF   WB_BYTES
#define ZBUF_BYTES 8192
#define XB_OFF     (ZBUF_OFF + ZBUF_BYTES)      // 598016
#define XB_BYTES   ((size_t)BATCH*HH*WW*CIN*2)  // 102760448
#define WS_NEED    ((size_t)XB_OFF + XB_BYTES)  // 103358464

__device__ inline void load_lds16(const void* g, void* l) {
    __builtin_amdgcn_global_load_lds(
        (const __attribute__((address_space(1))) void*)g,
        (__attribute__((address_space(3))) void*)l, 16, 0, 0);
}

// ---- pre-pass 1: weights OIHW fp32 -> [g][kh][kw][cout][cin] bf16 ----
__global__ __launch_bounds__(256) void k_wcvt(const float* __restrict__ w,
                                              ushort* __restrict__ wb) {
    int i = blockIdx.x * 256 + threadIdx.x;   // 294912 total
    int ci = i & 127;
    int t  = i >> 7;
    int co = t & 127;
    t >>= 7;                                  // t = g*9 + kh*3 + kw
    int kw = t % 3; t /= 3;
    int kh = t % 3;
    int g  = t / 3;
    int src = (((g*COG + co)*CG + ci)*3 + kh)*3 + kw;
    __hip_bfloat16 v = __float2bfloat16(w[src]);
    wb[i] = *reinterpret_cast<ushort*>(&v);
}

// ---- pre-pass 2: x NCHW fp32 -> NHWC bf16 (LDS transpose) ----
#define XPAD 113
__global__ __launch_bounds__(256) void k_xcvt(const float* __restrict__ x,
                                              ushort* __restrict__ xb) {
    __shared__ float tile[64 * XPAD];
    int bid = blockIdx.x;            // 16*112*4 = 7168
    int cc  = bid & 3;               // chunk of 64 channels
    int h   = (bid >> 2) % HH;
    int b   = bid / (4 * HH);
    int tid = threadIdx.x;

    const float* src = x + ((size_t)(b*CIN + cc*64) * HH + h) * WW;
    for (int tt = tid; tt < 64*28; tt += 256) {
        int c = tt / 28, v = tt % 28;
        float4 f = *reinterpret_cast<const float4*>(src + (size_t)c*HH*WW + v*4);
        float* d = &tile[c*XPAD + v*4];
        d[0]=f.x; d[1]=f.y; d[2]=f.z; d[3]=f.w;
    }
    __syncthreads();

    if (tid < 224) {
        int w = tid >> 1, half = tid & 1;
        ushort o[32];
#pragma unroll
        for (int j = 0; j < 32; ++j) {
            __hip_bfloat16 v = __float2bfloat16(tile[(half*32 + j)*XPAD + w]);
            o[j] = *reinterpret_cast<ushort*>(&v);
        }
        ushort* dst = xb + (((size_t)(b*HH + h)*WW + w)*CIN + cc*64 + half*32);
        const uint4* o4 = reinterpret_cast<const uint4*>(o);
        uint4* d4 = reinterpret_cast<uint4*>(dst);
        d4[0]=o4[0]; d4[1]=o4[1]; d4[2]=o4[2]; d4[3]=o4[3];
    }
}

// ---- stage one 3-tap weight group (swizzled source); 3 loads/thread ----
__device__ inline void stage_w3(const ushort* __restrict__ wb, ushort* dstbuf,
                                int g, int tap_base, int cin, int wave, int lane) {
    int co = wave*16 + (lane >> 2);
    int ts = (lane & 3) ^ ((lane >> 3) & 3);
#pragma unroll
    for (int i = 0; i < 3; ++i) {
        const ushort* src = wb + (((size_t)(g*9 + tap_base + i)*COG + co)*CG + cin + ts*8);
        load_lds16(src, dstbuf + (i*COG + wave*16)*CK);
    }
}

// ---- one x-prefetch slot (real task t<42 when enabled, else dummy load) ----
__device__ inline void xpre48(const ushort* __restrict__ xb, ushort* dstbuf,
                              ushort* dump, const ushort* __restrict__ zbuf,
                              int b, int g, int oh0, int cin, int t, int lane,
                              bool real) {
    if (real && t < 42) {
        int rr = t / 7, ii = t % 7;
        int h  = oh0 - 1 + rr;
        int qv = lane >> 2;
        int w_in = ii*16 + qv;
        int ts = (lane & 3) ^ (((2*rr + 1 + qv) >> 1) & 3);
        const ushort* src = (h >= 0 && h < HH)
            ? xb + (((size_t)(b*HH + h)*WW + w_in)*CIN + g*CG + cin + ts*8)
            : zbuf + lane*8;
        load_lds16(src, dstbuf + (rr*114 + 1 + ii*16)*CK);
    } else {
        load_lds16(zbuf + lane*8, dump);   // dummy: keeps per-wave vmcnt uniform
    }
}

#define WAITV(N) asm volatile("s_waitcnt vmcnt(" #N ")" ::: "memory");

// One tap-phase (m201 style): reads + stage-issue in the inter-barrier gap;
// dual barrier isolates the MFMA cluster; counted waits only at KW==2,
// executed BEFORE the closing barrier that publishes staged buffers.
#define TAPX(KH, KW, NT, NC)                                                \
  {                                                                         \
    int sB = lk ^ (((2*(wr + (KH)) + l15 + (KW)) >> 1) & 3);                \
    const ushort* bbase = xcur + ((wr + (KH))*114 + l15 + (KW))*CK + sB*8;  \
    bf16x8 xf[7];                                                           \
    _Pragma("unroll")                                                       \
    for (int i = 0; i < 7; ++i)                                             \
      xf[i] = *reinterpret_cast<const bf16x8*>(bbase + i*16*CK);            \
    const ushort* abase = wcur + ((KW)*COG + wm*64 + l15)*CK + sA*8;        \
    bf16x8 wf[4];                                                           \
    _Pragma("unroll")                                                       \
    for (int u = 0; u < 4; ++u)                                             \
      wf[u] = *reinterpret_cast<const bf16x8*>(abase + u*16*CK);            \
    if ((KW) == 0) stage_w3(wb, wnxt, g, (NT), (NC), wave, lane);           \
    if ((KW) <= 1)                                                          \
      xpre48(xb, xnxt, dump, zbuf, b, g, oh0, cinN,                         \
             wave + 8*((KH)*2 + (KW)), lane, c < 3);                        \
    __builtin_amdgcn_s_barrier();                                           \
    __builtin_amdgcn_s_setprio(1);                                          \
    _Pragma("unroll")                                                       \
    for (int u = 0; u < 4; ++u)                                             \
      _Pragma("unroll")                                                     \
      for (int i = 0; i < 7; ++i)                                           \
        acc[i][u] = __builtin_amdgcn_mfma_f32_16x16x32_bf16(                \
            xf[i], wf[u], acc[i][u], 0, 0, 0);                              \
    __builtin_amdgcn_s_setprio(0);                                          \
    if ((KW) == 2) { if ((KH) == 2) { WAITV(0) } else { WAITV(2) } }        \
    __builtin_amdgcn_s_barrier();                                           \
  }

#define GROUPSEC(KH, NT, NC) TAPX(KH,0,NT,NC) TAPX(KH,1,NT,NC) TAPX(KH,2,NT,NC)

// ---- main kernel: implicit-GEMM grouped conv, m201-style phase schedule ----
// 896 blocks (XCD-swizzled: contiguous q-runs per XCD -> halo rows L2-shared),
// 8 waves, m=4/n=7/RH=4 (0.39 ds_reads/MFMA). wsb = 3-tap ring dbuf; xs dbuf.
// Per tap: {11 ds_reads | stage issue | barrier | setprio 28 MFMA | [wait] |
// barrier}. vmcnt(2) drains each weight group before its consuming barrier
// (fixes r7's wait-after-barrier race); vmcnt(0) once per chunk boundary,
// >=1 tap after last issue. Swizzle + operand-swap epilogue verified r2-r7.
__global__ __launch_bounds__(512, 2) void k_conv(const ushort* __restrict__ xb,
                                                 const ushort* __restrict__ wb,
                                                 const float* __restrict__ bias,
                                                 float* __restrict__ out,
                                                 const ushort* __restrict__ zbuf) {
    __shared__ __align__(16) ushort xs[2][6*114*CK];     // 2 x 43776 B
    __shared__ __align__(16) ushort wsb[2][3*COG*CK];    // 2 x 24576 B
    __shared__ __align__(16) ushort dump[512];           // dummy sink (1 KB)

    int orig = (blockIdx.x & 7) * 112 + (blockIdx.x >> 3);   // XCD swizzle
    int g   = orig / 448;
    int r   = orig % 448;
    int b   = r / 28;
    int q   = r % 28;
    int oh0 = q * 4;

    int tid  = threadIdx.x;
    int wave = tid >> 6;
    int lane = tid & 63;
    int wm   = wave >> 2;          // cout half (0..1), 64 couts
    int wr   = wave & 3;           // output row within quad (0..3)
    int l15  = lane & 15;
    int lk   = lane >> 4;
    int sA   = lk ^ ((l15 >> 1) & 3);    // weight-read slot

    // zero pad columns (w=0,113) of both x buffers
    for (int t = tid; t < 768; t += 512) {
        int buf = t / 384, r2 = t % 384;
        int rr = r2 / 64, wc = (r2 >> 5) & 1, ch = r2 & 31;
        xs[buf][(rr*114 + wc*113)*CK + ch] = 0;
    }

    // bias per lane: co = g*COG + wm*64 + u*16 + l15
    float bvreg[4];
#pragma unroll
    for (int u = 0; u < 4; ++u)
        bvreg[u] = bias[g*COG + wm*64 + u*16 + l15];

    f32x4 acc[7][4];
#pragma unroll
    for (int i = 0; i < 7; ++i)
#pragma unroll
        for (int u = 0; u < 4; ++u) acc[i][u] = f32x4{0.f,0.f,0.f,0.f};

    // prologue: stage x chunk 0 (48 slots) + w group 0; full drain once
    for (int k2 = 0; k2 < 6; ++k2)
        xpre48(xb, xs[0], dump, zbuf, b, g, oh0, 0, wave + 8*k2, lane, true);
    stage_w3(wb, wsb[0], g, 0, 0, wave, lane);
    WAITV(0)
    __builtin_amdgcn_s_barrier();

#pragma unroll 1
    for (int c = 0; c < 4; ++c) {
        const ushort* xcur = xs[c & 1];
        ushort* xnxt = xs[(c & 1) ^ 1];
        int cin  = c * CK;
        int cinN = ((c + 1) & 3) * CK;
        (void)cin;

        {   // kh = 0: reads wsb[(c)&1]; stages taps 3-5 -> other
            const ushort* wcur = wsb[c & 1];
            ushort* wnxt = wsb[(c & 1) ^ 1];
            GROUPSEC(0, 3, c*CK)
        }
        {   // kh = 1
            const ushort* wcur = wsb[(c + 1) & 1];
            ushort* wnxt = wsb[c & 1];
            GROUPSEC(1, 6, c*CK)
        }
        {   // kh = 2: stages next chunk's taps 0-2 (harmless wrap at c=3)
            const ushort* wcur = wsb[c & 1];
            ushort* wnxt = wsb[(c + 1) & 1];
            GROUPSEC(2, 0, cinN)
        }
    }

    // epilogue (verified r7): acc[i][u] -> 28 dwordx4 stores, 4 contiguous px
    int oh = oh0 + wr;
#pragma unroll
    for (int u = 0; u < 4; ++u) {
        int co = g*COG + wm*64 + u*16 + l15;
        float bv = bvreg[u];
        float* obase = out + (((size_t)(b*CIN + co)*HH + oh)*WW + lk*4);
#pragma unroll
        for (int i = 0; i < 7; ++i) {
            f32x4 v;
            v[0] = acc[i][u][0] + bv;
            v[1] = acc[i][u][1] + bv;
            v[2] = acc[i][u][2] + bv;
            v[3] = acc[i][u][3] + bv;
            *reinterpret_cast<f32x4*>(obase + i*16) = v;
        }
    }
}

// ---- fallback: direct fp32 conv (used only if ws is too small) ----
__global__ __launch_bounds__(128) void k_direct(const float* __restrict__ x,
                                                const float* __restrict__ w,
                                                const float* __restrict__ bias,
                                                float* __restrict__ out) {
    int bid = blockIdx.x;          // B*Cout*H
    int oh  = bid % HH;
    int t   = bid / HH;
    int co  = t % CIN;
    int b   = t / CIN;
    int ow  = threadIdx.x;
    if (ow >= WW) return;
    int g = co / COG;
    float s = bias[co];
    const float* wp = w + (size_t)co*CG*9;
    const float* xp = x + ((size_t)b*CIN + g*CG)*HH*WW;
    for (int ci = 0; ci < CG; ++ci) {
        const float* xr = xp + (size_t)ci*HH*WW;
        const float* wr_ = wp + ci*9;
#pragma unroll
        for (int kh = 0; kh < 3; ++kh) {
            int ih = oh + kh - 1;
            if (ih < 0 || ih >= HH) continue;
#pragma unroll
            for (int kw = 0; kw < 3; ++kw) {
                int iw = ow + kw - 1;
                if (iw < 0 || iw >= WW) continue;
                s += xr[ih*WW + iw] * wr_[kh*3 + kw];
            }
        }
    }
    out[(((size_t)b*CIN + co)*HH + oh)*WW + ow] = s;
}

extern "C" void kernel_launch(void* const* d_in, const int* in_sizes, int n_in,
                              void* d_out, int out_size, void* d_ws, size_t ws_size,
                              hipStream_t stream) {
    const float* x    = (const float*)d_in[0];
    const float* w    = (const float*)d_in[1];
    const float* bias = (const float*)d_in[2];
    float* out        = (float*)d_out;

    if (ws_size >= WS_NEED) {
        ushort* wb   = (ushort*)d_ws;
        ushort* zb   = (ushort*)((char*)d_ws + ZBUF_OFF);
        ushort* xbuf = (ushort*)((char*)d_ws + XB_OFF);
        hipMemsetAsync(zb, 0, ZBUF_BYTES, stream);
        k_wcvt<<<1152, 256, 0, stream>>>(w, wb);
        k_xcvt<<<BATCH*HH*4, 256, 0, stream>>>(x, xbuf);
        k_conv<<<896, 512, 0, stream>>>(xbuf, wb, bias, out, zb);
    } else {
        k_direct<<<BATCH*CIN*HH, 128, 0, stream>>>(x, w, bias, out);
    }
}